// Round 1
// baseline (512.105 us; speedup 1.0000x reference)
//
#include <hip/hip_runtime.h>
#include <hip/hip_bf16.h>

typedef short bf16x8 __attribute__((ext_vector_type(8)));
typedef float f32x4  __attribute__((ext_vector_type(4)));

#define T_SEQ 4096
#define NB    4
#define E_DIM 2048
#define D_DIM 128
#define M_TOT (NB * T_SEQ)  // 16384

__device__ __forceinline__ ushort f2bf(float f) {
  union { float f; unsigned u; } c; c.f = f;
  unsigned u = c.u;
  unsigned r = (u + 0x7FFFu + ((u >> 16) & 1u)) >> 16;  // RNE
  return (ushort)r;
}

// ---------------- kernel 1: Wt[o*128+n][k] = W_o[k][n]  (bf16) ----------------
__global__ __launch_bounds__(256) void build_wt(const float* __restrict__ Wq,
                                                const float* __restrict__ Wk,
                                                const float* __restrict__ Wv,
                                                ushort* __restrict__ Wt) {
  int idx = blockIdx.x * 256 + threadIdx.x;  // over 3*2048*128
  int o   = idx >> 18;                       // 2048*128 = 2^18
  int rem = idx & 262143;                    // k*128 + n (coalesced read)
  int n   = rem & 127;
  int k   = rem >> 7;
  const float* W = (o == 0) ? Wq : ((o == 1) ? Wk : Wv);
  Wt[(size_t)((o << 7) + n) * E_DIM + k] = f2bf(W[rem]);
}

// ---------------- kernel 2: QKV GEMM  [16384 x 2048] x [2048 x 384] ----------------
// tile 128(M) x 192(N), BK=64, 4 waves in 2x2, each wave 64x96 (4x6 mfma tiles)
__global__ __launch_bounds__(256) void qkv_gemm(const float* __restrict__ x,
                                                const ushort* __restrict__ Wt,
                                                ushort* __restrict__ Q,
                                                ushort* __restrict__ K,
                                                ushort* __restrict__ V) {
  __shared__ ushort As[128][72];   // [m][k] bf16, pad +8
  __shared__ ushort Bs[192][72];   // [n][k] bf16, pad +8

  const int tid  = threadIdx.x;
  const int wave = tid >> 6, lane = tid & 63;
  const int quad = lane >> 4, l16 = lane & 15;
  const int wm = wave >> 1, wn = wave & 1;
  const int m0 = blockIdx.x * 128;
  const int n0 = blockIdx.y * 192;

  f32x4 acc[4][6] = {};

  for (int k0 = 0; k0 < E_DIM; k0 += 64) {
    __syncthreads();
    // stage A: 128x64 fp32 -> bf16 ; 2048 float4 chunks, 8/thread
    for (int i = 0; i < 8; i++) {
      int c   = tid + i * 256;
      int r   = c >> 4;
      int col = (c & 15) * 4;
      float4 v = *(const float4*)(x + (size_t)(m0 + r) * E_DIM + k0 + col);
      ushort4 b4;
      b4.x = f2bf(v.x); b4.y = f2bf(v.y); b4.z = f2bf(v.z); b4.w = f2bf(v.w);
      *(ushort4*)(&As[r][col]) = b4;
    }
    // stage B: 192x64 bf16 ; 1536 uint4 chunks, 6/thread
    for (int i = 0; i < 6; i++) {
      int c   = tid + i * 256;
      int r   = c >> 3;
      int col = (c & 7) * 8;
      *(uint4*)(&Bs[r][col]) = *(const uint4*)(Wt + (size_t)(n0 + r) * E_DIM + k0 + col);
    }
    __syncthreads();

    for (int kk = 0; kk < 2; kk++) {
      const int kc = kk * 32 + quad * 8;
      bf16x8 bfr[6];
      for (int ni = 0; ni < 6; ni++)
        bfr[ni] = *(const bf16x8*)(&Bs[wn * 96 + ni * 16 + l16][kc]);
      for (int mi = 0; mi < 4; mi++) {
        bf16x8 af = *(const bf16x8*)(&As[wm * 64 + mi * 16 + l16][kc]);
        for (int ni = 0; ni < 6; ni++)
          acc[mi][ni] = __builtin_amdgcn_mfma_f32_16x16x32_bf16(af, bfr[ni], acc[mi][ni], 0, 0, 0);
      }
    }
  }

  // epilogue: C/D layout row = quad*4+r, col = l16
  for (int mi = 0; mi < 4; mi++) {
    for (int ni = 0; ni < 6; ni++) {
      int colall = n0 + wn * 96 + ni * 16 + l16;
      int o = colall >> 7, d = colall & 127;
      ushort* dst = (o == 0) ? Q : ((o == 1) ? K : V);
      for (int r = 0; r < 4; r++) {
        int row = m0 + wm * 64 + mi * 16 + quad * 4 + r;
        dst[(size_t)row * D_DIM + d] = f2bf(acc[mi][ni][r]);
      }
    }
  }
}

// ---------------- kernel 3: Vt[b][d][t] = V[b][t][d]  (bf16) ----------------
__global__ __launch_bounds__(256) void v_transpose(const ushort* __restrict__ V,
                                                   ushort* __restrict__ Vt) {
  __shared__ ushort tile[64][72];
  const int tid = threadIdx.x;
  const int t0 = blockIdx.x * 64, d0 = blockIdx.y * 64, b = blockIdx.z;
  for (int i = 0; i < 2; i++) {
    int c = tid + i * 256;      // 512 chunks of 8 bf16
    int r = c >> 3, cc = (c & 7) * 8;
    *(uint4*)(&tile[r][cc]) = *(const uint4*)(V + (size_t)(b * T_SEQ + t0 + r) * D_DIM + d0 + cc);
  }
  __syncthreads();
  for (int i = 0; i < 2; i++) {
    int c = tid + i * 256;
    int dr = c >> 3, tc = (c & 7) * 8;
    ushort tmp[8];
    for (int j = 0; j < 8; j++) tmp[j] = tile[tc + j][dr];
    *(uint4*)(Vt + (size_t)(b * D_DIM + d0 + dr) * T_SEQ + t0 + tc) = *(const uint4*)tmp;
  }
}

// ---------------- kernel 4: flash attention, causal ----------------
// block = 256 thr (4 waves), BM=64 q rows (16/wave), BN=64 k cols/iter
__global__ __launch_bounds__(256) void attn(const ushort* __restrict__ Q,
                                            const ushort* __restrict__ K,
                                            const ushort* __restrict__ Vt,
                                            float* __restrict__ out) {
  __shared__ ushort Kt[64][136];     // [t][d] bf16
  __shared__ ushort Vts[128][72];    // [d][t] bf16
  __shared__ ushort Pls[4][16][72];  // per-wave P [qrow][t]

  const int qt = blockIdx.x, b = blockIdx.y;
  const int tid = threadIdx.x;
  const int wave = tid >> 6, lane = tid & 63;
  const int quad = lane >> 4, l16 = lane & 15;

  // preload Q fragments (A-layout: m=l16, k=kk*32+quad*8+j)
  const int qrow = qt * 64 + wave * 16 + l16;
  bf16x8 qf[4];
  for (int kk = 0; kk < 4; kk++)
    qf[kk] = *(const bf16x8*)(Q + (size_t)(b * T_SEQ + qrow) * D_DIM + kk * 32 + quad * 8);

  float m_old[4], l_sum[4];
  f32x4 o_acc[8] = {};
  for (int r = 0; r < 4; r++) { m_old[r] = -1e30f; l_sum[r] = 0.f; }
  const float scale2 = 0.08838834764831845f * 1.4426950408889634f;  // 1/sqrt(128)*log2(e)

  for (int kt = 0; kt <= qt; kt++) {
    __syncthreads();  // previous PV done before restage
    // stage K tile: 64 x 128 bf16, 1024 chunks, 4/thread
    for (int i = 0; i < 4; i++) {
      int c = tid + i * 256;
      int r = c >> 4, col = (c & 15) * 8;
      *(uint4*)(&Kt[r][col]) = *(const uint4*)(K + (size_t)(b * T_SEQ + kt * 64 + r) * D_DIM + col);
    }
    // stage Vt tile: 128 x 64 bf16, 1024 chunks, 4/thread
    for (int i = 0; i < 4; i++) {
      int c = tid + i * 256;
      int dr = c >> 3, col = (c & 7) * 8;
      *(uint4*)(&Vts[dr][col]) = *(const uint4*)(Vt + (size_t)(b * D_DIM + dr) * T_SEQ + kt * 64 + col);
    }
    __syncthreads();

    // S = Q K^T  (per wave: 16 q rows x 64 cols, 4 ni tiles)
    f32x4 s[4] = {};
    for (int kk = 0; kk < 4; kk++) {
      const int kc = kk * 32 + quad * 8;
      for (int ni = 0; ni < 4; ni++) {
        bf16x8 bf = *(const bf16x8*)(&Kt[ni * 16 + l16][kc]);
        s[ni] = __builtin_amdgcn_mfma_f32_16x16x32_bf16(qf[kk], bf, s[ni], 0, 0, 0);
      }
    }
    // scale (base-2) + causal mask (only diagonal tile)
    for (int ni = 0; ni < 4; ni++) {
      for (int r = 0; r < 4; r++) {
        float v = s[ni][r] * scale2;
        if (kt == qt) {
          int kidx = kt * 64 + ni * 16 + l16;
          int qidx = qt * 64 + wave * 16 + quad * 4 + r;
          if (kidx > qidx) v = -1e30f;
        }
        s[ni][r] = v;
      }
    }
    // row max
    float mrow[4];
    for (int r = 0; r < 4; r++) {
      float m = s[0][r];
      for (int ni = 1; ni < 4; ni++) m = fmaxf(m, s[ni][r]);
      for (int off = 1; off < 16; off <<= 1) m = fmaxf(m, __shfl_xor(m, off));
      mrow[r] = m;
    }
    float alpha[4];
    for (int r = 0; r < 4; r++) {
      float mn = fmaxf(m_old[r], mrow[r]);
      alpha[r] = exp2f(m_old[r] - mn);
      m_old[r] = mn;
    }
    // P = exp2(s - m), row sums, rescale O
    float rs[4] = {0.f, 0.f, 0.f, 0.f};
    for (int ni = 0; ni < 4; ni++)
      for (int r = 0; r < 4; r++) {
        float p = exp2f(s[ni][r] - m_old[r]);
        s[ni][r] = p;
        rs[r] += p;
      }
    for (int r = 0; r < 4; r++) {
      for (int off = 1; off < 16; off <<= 1) rs[r] += __shfl_xor(rs[r], off);
      l_sum[r] = l_sum[r] * alpha[r] + rs[r];
    }
    for (int ni = 0; ni < 8; ni++)
      for (int r = 0; r < 4; r++) o_acc[ni][r] *= alpha[r];
    // P -> LDS (per-wave private), C-layout scatter
    for (int ni = 0; ni < 4; ni++)
      for (int r = 0; r < 4; r++)
        Pls[wave][quad * 4 + r][ni * 16 + l16] = f2bf(s[ni][r]);
    __syncthreads();
    // O += P V   (A = P from LDS, B = V from Vts)
    for (int kk2 = 0; kk2 < 2; kk2++) {
      const int kc = kk2 * 32 + quad * 8;
      bf16x8 pf = *(const bf16x8*)(&Pls[wave][l16][kc]);
      for (int ni = 0; ni < 8; ni++) {
        bf16x8 vf = *(const bf16x8*)(&Vts[ni * 16 + l16][kc]);
        o_acc[ni] = __builtin_amdgcn_mfma_f32_16x16x32_bf16(pf, vf, o_acc[ni], 0, 0, 0);
      }
    }
  }

  // epilogue: out = O / l
  for (int ni = 0; ni < 8; ni++) {
    for (int r = 0; r < 4; r++) {
      int q = qt * 64 + wave * 16 + quad * 4 + r;
      int d = ni * 16 + l16;
      out[(size_t)(b * T_SEQ + q) * D_DIM + d] = o_acc[ni][r] / l_sum[r];
    }
  }
}

extern "C" void kernel_launch(void* const* d_in, const int* in_sizes, int n_in,
                              void* d_out, int out_size, void* d_ws, size_t ws_size,
                              hipStream_t stream) {
  const float* x  = (const float*)d_in[0];
  const float* Wq = (const float*)d_in[1];
  const float* Wk = (const float*)d_in[2];
  const float* Wv = (const float*)d_in[3];
  float* out = (float*)d_out;

  ushort* Q  = (ushort*)d_ws;                       // 16384*128 bf16
  ushort* Kb = Q  + (size_t)M_TOT * D_DIM;
  ushort* Vb = Kb + (size_t)M_TOT * D_DIM;
  ushort* Vt = Vb + (size_t)M_TOT * D_DIM;
  ushort* Wt = Vt + (size_t)M_TOT * D_DIM;          // 384*2048 bf16

  hipLaunchKernelGGL(build_wt,    dim3(3072),      dim3(256), 0, stream, Wq, Wk, Wv, Wt);
  hipLaunchKernelGGL(qkv_gemm,    dim3(128, 2),    dim3(256), 0, stream, x, Wt, Q, Kb, Vb);
  hipLaunchKernelGGL(v_transpose, dim3(64, 2, 4),  dim3(256), 0, stream, Vb, Vt);
  hipLaunchKernelGGL(attn,        dim3(64, 4),     dim3(256), 0, stream, Q, Kb, Vt, out);
}

// Round 2
// 404.536 us; speedup vs baseline: 1.2659x; 1.2659x over previous
//
#include <hip/hip_runtime.h>
#include <hip/hip_bf16.h>

typedef short bf16x8 __attribute__((ext_vector_type(8)));
typedef float f32x4  __attribute__((ext_vector_type(4)));

#define T_SEQ 4096
#define NB    4
#define E_DIM 2048
#define D_DIM 128
#define M_TOT (NB * T_SEQ)  // 16384
#define CHUNK 16            // k-tiles of 64 per split-K chunk (1024 keys)
#define NCHUNK 4            // 64 k-tiles / 16

__device__ __forceinline__ ushort f2bf(float f) {
  union { float f; unsigned u; } c; c.f = f;
  unsigned u = c.u;
  unsigned r = (u + 0x7FFFu + ((u >> 16) & 1u)) >> 16;  // RNE
  return (ushort)r;
}
__device__ __forceinline__ float bf2f(ushort u) {
  union { unsigned u; float f; } c; c.u = ((unsigned)u) << 16;
  return c.f;
}

// ---------------- kernel 1: Wt[o*128+n][k] = W_o[k][n]  (bf16) ----------------
__global__ __launch_bounds__(256) void build_wt(const float* __restrict__ Wq,
                                                const float* __restrict__ Wk,
                                                const float* __restrict__ Wv,
                                                ushort* __restrict__ Wt) {
  int idx = blockIdx.x * 256 + threadIdx.x;  // over 3*2048*128
  int o   = idx >> 18;
  int rem = idx & 262143;                    // k*128 + n (coalesced read)
  int n   = rem & 127;
  int k   = rem >> 7;
  const float* W = (o == 0) ? Wq : ((o == 1) ? Wk : Wv);
  Wt[(size_t)((o << 7) + n) * E_DIM + k] = f2bf(W[rem]);
}

// ---------------- kernel 2: QKV GEMM  [16384 x 2048] x [2048 x 384] ----------------
// tile 64(M) x 192(N), BK=64, grid (256,2)=512 blocks (2/CU), 4 waves 2x2, wave 32x96
__global__ __launch_bounds__(256) void qkv_gemm(const float* __restrict__ x,
                                                const ushort* __restrict__ Wt,
                                                ushort* __restrict__ Q,
                                                ushort* __restrict__ K,
                                                ushort* __restrict__ V) {
  __shared__ ushort As[64][72];    // [m][k] bf16
  __shared__ ushort Bs[192][72];   // [n][k] bf16

  const int tid  = threadIdx.x;
  const int wave = tid >> 6, lane = tid & 63;
  const int quad = lane >> 4, l16 = lane & 15;
  const int wm = wave >> 1, wn = wave & 1;
  const int m0 = blockIdx.x * 64;
  const int n0 = blockIdx.y * 192;

  f32x4 acc[2][6] = {};

  for (int k0 = 0; k0 < E_DIM; k0 += 64) {
    __syncthreads();
    // stage A: 64x64 fp32 -> bf16 ; 1024 float4 chunks, 4/thread
    for (int i = 0; i < 4; i++) {
      int c   = tid + i * 256;
      int r   = c >> 4;
      int col = (c & 15) * 4;
      float4 v = *(const float4*)(x + (size_t)(m0 + r) * E_DIM + k0 + col);
      ushort4 b4;
      b4.x = f2bf(v.x); b4.y = f2bf(v.y); b4.z = f2bf(v.z); b4.w = f2bf(v.w);
      *(ushort4*)(&As[r][col]) = b4;
    }
    // stage B: 192x64 bf16 ; 1536 uint4 chunks, 6/thread
    for (int i = 0; i < 6; i++) {
      int c   = tid + i * 256;
      int r   = c >> 3;
      int col = (c & 7) * 8;
      *(uint4*)(&Bs[r][col]) = *(const uint4*)(Wt + (size_t)(n0 + r) * E_DIM + k0 + col);
    }
    __syncthreads();

    for (int kk = 0; kk < 2; kk++) {
      const int kc = kk * 32 + quad * 8;
      bf16x8 bfr[6];
      for (int ni = 0; ni < 6; ni++)
        bfr[ni] = *(const bf16x8*)(&Bs[wn * 96 + ni * 16 + l16][kc]);
      for (int mi = 0; mi < 2; mi++) {
        bf16x8 af = *(const bf16x8*)(&As[wm * 32 + mi * 16 + l16][kc]);
        for (int ni = 0; ni < 6; ni++)
          acc[mi][ni] = __builtin_amdgcn_mfma_f32_16x16x32_bf16(af, bfr[ni], acc[mi][ni], 0, 0, 0);
      }
    }
  }

  for (int mi = 0; mi < 2; mi++) {
    for (int ni = 0; ni < 6; ni++) {
      int colall = n0 + wn * 96 + ni * 16 + l16;
      int o = colall >> 7, d = colall & 127;
      ushort* dst = (o == 0) ? Q : ((o == 1) ? K : V);
      for (int r = 0; r < 4; r++) {
        int row = m0 + wm * 32 + mi * 16 + quad * 4 + r;
        dst[(size_t)row * D_DIM + d] = f2bf(acc[mi][ni][r]);
      }
    }
  }
}

// ---------------- kernel 3: Vt[b][d][t] = V[b][t][d]  (bf16) ----------------
__global__ __launch_bounds__(256) void v_transpose(const ushort* __restrict__ V,
                                                   ushort* __restrict__ Vt) {
  __shared__ ushort tile[64][72];
  const int tid = threadIdx.x;
  const int t0 = blockIdx.x * 64, d0 = blockIdx.y * 64, b = blockIdx.z;
  for (int i = 0; i < 2; i++) {
    int c = tid + i * 256;
    int r = c >> 3, cc = (c & 7) * 8;
    *(uint4*)(&tile[r][cc]) = *(const uint4*)(V + (size_t)(b * T_SEQ + t0 + r) * D_DIM + d0 + cc);
  }
  __syncthreads();
  for (int i = 0; i < 2; i++) {
    int c = tid + i * 256;
    int dr = c >> 3, tc = (c & 7) * 8;
    ushort tmp[8];
    for (int j = 0; j < 8; j++) tmp[j] = tile[tc + j][dr];
    *(uint4*)(Vt + (size_t)(b * D_DIM + d0 + dr) * T_SEQ + t0 + tc) = *(const uint4*)tmp;
  }
}

// ---------------- kernel 4: flash attention partial (split-K) ----------------
// grid (qt=64, cq=4, b=4); block 4 waves, BM=64 (16 q rows/wave), BN=64/iter
// chunk cq covers k-tiles [cq*16, min(qt, cq*16+15)]
__global__ __launch_bounds__(256) void attn_partial(const ushort* __restrict__ Q,
                                                    const ushort* __restrict__ K,
                                                    const ushort* __restrict__ Vt,
                                                    ushort* __restrict__ Po,
                                                    float* __restrict__ Ml,
                                                    float* __restrict__ Ll) {
  const int qt = blockIdx.x, cq = blockIdx.y, b = blockIdx.z;
  if (cq * CHUNK > qt) return;

  __shared__ ushort Kt[64][136];     // [t][d]
  __shared__ ushort Vts[128][72];    // [d][t]
  __shared__ ushort Pls[4][16][72];  // per-wave P [qrow][t]

  const int tid = threadIdx.x;
  const int wave = tid >> 6, lane = tid & 63;
  const int quad = lane >> 4, l16 = lane & 15;

  const int qrow = qt * 64 + wave * 16 + l16;
  bf16x8 qf[4];
  for (int kk = 0; kk < 4; kk++)
    qf[kk] = *(const bf16x8*)(Q + (size_t)(b * T_SEQ + qrow) * D_DIM + kk * 32 + quad * 8);

  float m_old[4], l_sum[4];
  f32x4 o_acc[8] = {};
  for (int r = 0; r < 4; r++) { m_old[r] = -1e30f; l_sum[r] = 0.f; }
  const float scale2 = 0.08838834764831845f * 1.4426950408889634f;

  const int kt0 = cq * CHUNK;
  const int kt1 = min(qt, cq * CHUNK + CHUNK - 1);

  for (int kt = kt0; kt <= kt1; kt++) {
    __syncthreads();
    for (int i = 0; i < 4; i++) {
      int c = tid + i * 256;
      int r = c >> 4, col = (c & 15) * 8;
      *(uint4*)(&Kt[r][col]) = *(const uint4*)(K + (size_t)(b * T_SEQ + kt * 64 + r) * D_DIM + col);
    }
    for (int i = 0; i < 4; i++) {
      int c = tid + i * 256;
      int dr = c >> 3, col = (c & 7) * 8;
      *(uint4*)(&Vts[dr][col]) = *(const uint4*)(Vt + (size_t)(b * D_DIM + dr) * T_SEQ + kt * 64 + col);
    }
    __syncthreads();

    f32x4 s[4] = {};
    for (int kk = 0; kk < 4; kk++) {
      const int kc = kk * 32 + quad * 8;
      for (int ni = 0; ni < 4; ni++) {
        bf16x8 bf = *(const bf16x8*)(&Kt[ni * 16 + l16][kc]);
        s[ni] = __builtin_amdgcn_mfma_f32_16x16x32_bf16(qf[kk], bf, s[ni], 0, 0, 0);
      }
    }
    for (int ni = 0; ni < 4; ni++) {
      for (int r = 0; r < 4; r++) {
        float v = s[ni][r] * scale2;
        if (kt == qt) {
          int kidx = kt * 64 + ni * 16 + l16;
          int qidx = qt * 64 + wave * 16 + quad * 4 + r;
          if (kidx > qidx) v = -1e30f;
        }
        s[ni][r] = v;
      }
    }
    float mrow[4];
    for (int r = 0; r < 4; r++) {
      float m = s[0][r];
      for (int ni = 1; ni < 4; ni++) m = fmaxf(m, s[ni][r]);
      for (int off = 1; off < 16; off <<= 1) m = fmaxf(m, __shfl_xor(m, off));
      mrow[r] = m;
    }
    float alpha[4];
    for (int r = 0; r < 4; r++) {
      float mn = fmaxf(m_old[r], mrow[r]);
      alpha[r] = exp2f(m_old[r] - mn);
      m_old[r] = mn;
    }
    float rs[4] = {0.f, 0.f, 0.f, 0.f};
    for (int ni = 0; ni < 4; ni++)
      for (int r = 0; r < 4; r++) {
        float p = exp2f(s[ni][r] - m_old[r]);
        s[ni][r] = p;
        rs[r] += p;
      }
    for (int r = 0; r < 4; r++) {
      for (int off = 1; off < 16; off <<= 1) rs[r] += __shfl_xor(rs[r], off);
      l_sum[r] = l_sum[r] * alpha[r] + rs[r];
    }
    for (int ni = 0; ni < 8; ni++)
      for (int r = 0; r < 4; r++) o_acc[ni][r] *= alpha[r];
    // P -> per-wave LDS (C-layout scatter); wave-private, no block barrier needed
    for (int ni = 0; ni < 4; ni++)
      for (int r = 0; r < 4; r++)
        Pls[wave][quad * 4 + r][ni * 16 + l16] = f2bf(s[ni][r]);
    for (int kk2 = 0; kk2 < 2; kk2++) {
      const int kc = kk2 * 32 + quad * 8;
      bf16x8 pf = *(const bf16x8*)(&Pls[wave][l16][kc]);
      for (int ni = 0; ni < 8; ni++) {
        bf16x8 vf = *(const bf16x8*)(&Vts[ni * 16 + l16][kc]);
        o_acc[ni] = __builtin_amdgcn_mfma_f32_16x16x32_bf16(pf, vf, o_acc[ni], 0, 0, 0);
      }
    }
  }

  // epilogue: un-normalized partials
  const int slot = (b * 64 + qt) * NCHUNK + cq;
  for (int ni = 0; ni < 8; ni++)
    for (int r = 0; r < 4; r++) {
      int ql = wave * 16 + quad * 4 + r;
      Po[(size_t)slot * 8192 + ql * D_DIM + ni * 16 + l16] = f2bf(o_acc[ni][r]);
    }
  if (l16 == 0) {
    for (int r = 0; r < 4; r++) {
      int ql = wave * 16 + quad * 4 + r;
      Ml[slot * 64 + ql] = m_old[r];
      Ll[slot * 64 + ql] = l_sum[r];
    }
  }
}

// ---------------- kernel 5: split-K reduce ----------------
// grid (qt=64, b=4), 256 thr; thread: 1 row x 32 cols
__global__ __launch_bounds__(256) void attn_reduce(const ushort* __restrict__ Po,
                                                   const float* __restrict__ Ml,
                                                   const float* __restrict__ Ll,
                                                   float* __restrict__ out) {
  const int qt = blockIdx.x, b = blockIdx.y;
  const int nc = (qt >> 4) + 1;
  const int tid = threadIdx.x;
  const int row = tid >> 2;
  const int c0  = (tid & 3) * 32;
  const int base_slot = (b * 64 + qt) * NCHUNK;

  float mv[NCHUNK], lv[NCHUNK], w[NCHUNK];
  float m = -1e30f;
  for (int c = 0; c < nc; c++) {
    mv[c] = Ml[(base_slot + c) * 64 + row];
    lv[c] = Ll[(base_slot + c) * 64 + row];
    m = fmaxf(m, mv[c]);
  }
  float L = 0.f;
  for (int c = 0; c < nc; c++) { w[c] = exp2f(mv[c] - m); L += w[c] * lv[c]; }
  const float inv = 1.0f / L;

  const size_t orow = (size_t)(b * T_SEQ + qt * 64 + row) * D_DIM;
  for (int cc = 0; cc < 32; cc += 8) {
    float a[8] = {0,0,0,0,0,0,0,0};
    for (int c = 0; c < nc; c++) {
      const ushort* p = Po + (size_t)(base_slot + c) * 8192 + row * D_DIM + c0 + cc;
      ushort u[8];
      *(uint4*)u = *(const uint4*)p;
      for (int j = 0; j < 8; j++) a[j] += w[c] * bf2f(u[j]);
    }
    float4 o0, o1;
    o0.x = a[0] * inv; o0.y = a[1] * inv; o0.z = a[2] * inv; o0.w = a[3] * inv;
    o1.x = a[4] * inv; o1.y = a[5] * inv; o1.z = a[6] * inv; o1.w = a[7] * inv;
    *(float4*)(out + orow + c0 + cc)     = o0;
    *(float4*)(out + orow + c0 + cc + 4) = o1;
  }
}

extern "C" void kernel_launch(void* const* d_in, const int* in_sizes, int n_in,
                              void* d_out, int out_size, void* d_ws, size_t ws_size,
                              hipStream_t stream) {
  const float* x  = (const float*)d_in[0];
  const float* Wq = (const float*)d_in[1];
  const float* Wk = (const float*)d_in[2];
  const float* Wv = (const float*)d_in[3];
  float* out = (float*)d_out;

  ushort* Q  = (ushort*)d_ws;                       // 16384*128 bf16 each
  ushort* Kb = Q  + (size_t)M_TOT * D_DIM;
  ushort* Vb = Kb + (size_t)M_TOT * D_DIM;
  ushort* Vt = Vb + (size_t)M_TOT * D_DIM;
  ushort* Wt = Vt + (size_t)M_TOT * D_DIM;          // 384*2048 bf16
  ushort* Po = Wt + (size_t)384 * E_DIM;            // 1024 slots * 8192 bf16
  float*  Ml = (float*)(Po + (size_t)NB * 64 * NCHUNK * 8192);  // 1024*64 f32
  float*  Ll = Ml + (size_t)NB * 64 * NCHUNK * 64;

  hipLaunchKernelGGL(build_wt,     dim3(3072),        dim3(256), 0, stream, Wq, Wk, Wv, Wt);
  hipLaunchKernelGGL(qkv_gemm,     dim3(256, 2),      dim3(256), 0, stream, x, Wt, Q, Kb, Vb);
  hipLaunchKernelGGL(v_transpose,  dim3(64, 2, 4),    dim3(256), 0, stream, Vb, Vt);
  hipLaunchKernelGGL(attn_partial, dim3(64, NCHUNK, 4), dim3(256), 0, stream, Q, Kb, Vt, Po, Ml, Ll);
  hipLaunchKernelGGL(attn_reduce,  dim3(64, 4),       dim3(256), 0, stream, Po, Ml, Ll, out);
}